// Round 5
// baseline (513.778 us; speedup 1.0000x reference)
//
#include <hip/hip_runtime.h>
#include <hip/hip_bf16.h>
#include <cstdint>

#define B_ 8
#define T_ 2048
#define E_ 256
#define K_ 512
#define KS_ 9
#define L_ 8192
#define PAD_ 4
#define TP_ (T_ + 2 * PAD_)   // 2056
#define KK_ (E_ * KS_)        // 2304

// fp8 scaling: feats stored as fp8*64, U/final stored as fp8*16.
// S and V accumulators are 1024x true value -> multiply by 2^-10 in epilogue.
#define FEAT_SCALE 64.0f
#define W_SCALE 16.0f
#define INV_SS 9.765625e-4f         // 2^-10
#define INV_SS_LOG2E 1.40888719e-3f // 2^-10 * log2(e)

typedef __bf16 bf16x8 __attribute__((ext_vector_type(8)));
typedef float f32x4 __attribute__((ext_vector_type(4)));
typedef float f32x16 __attribute__((ext_vector_type(16)));
typedef int i32x4 __attribute__((ext_vector_type(4)));
typedef int i32x8 __attribute__((ext_vector_type(8)));

__device__ __forceinline__ unsigned short f2bf(float f) {
  union { float f; unsigned int u; } a; a.f = f;
  unsigned int r = (a.u + 0x7FFFu + ((a.u >> 16) & 1u)) >> 16;
  return (unsigned short)r;
}

__device__ __forceinline__ unsigned char f2fp8(float v) {
  return (unsigned char)(__builtin_amdgcn_cvt_pk_fp8_f32(v, v, 0, false) & 0xFF);
}

__device__ __forceinline__ unsigned int pk4_fp8(float a, float b, float c, float d) {
  int v = __builtin_amdgcn_cvt_pk_fp8_f32(a, b, 0, false);
  v = __builtin_amdgcn_cvt_pk_fp8_f32(c, d, v, true);
  return (unsigned int)v;
}

__device__ __forceinline__ void gld_lds16(const void* g, void* l) {
  __builtin_amdgcn_global_load_lds(
      (const __attribute__((address_space(1))) unsigned int*)g,
      (__attribute__((address_space(3))) unsigned int*)l, 16, 0, 0);
}

__device__ __forceinline__ f32x4 mfma_bf16(bf16x8 a, bf16x8 b, f32x4 c) {
  return __builtin_amdgcn_mfma_f32_16x16x32_bf16(a, b, c, 0, 0, 0);
}

// MX-scaled fp8 MFMA, K=64, unity e8m0 scales (0x7F -> 2^0). 2x non-scaled rate.
__device__ __forceinline__ f32x16 mfma_sc64(i32x8 a, i32x8 b, f32x16 c) {
  return __builtin_amdgcn_mfma_scale_f32_32x32x64_f8f6f4(a, b, c, 0, 0, 0, 127, 0, 127);
}

// Pair-unit-major layouts: each lane's 32 B MFMA fragment is CONTIGUOUS, so
// fa/uf/wf are single i32x8 loads (2x ds_read_b128, no repack movs).
// Bank floor: 64 lanes x 16 B = 1024 B per ds_read_b128 = 8 phases, exact.
// (Bank-conflict-free verified in R3: SQ_LDS_BANK_CONFLICT 8.9M -> 0.)
// feats per batch: [tc = t>>6][p = k>>5][t&63][k&31]  (32 KB per t-chunk)
__device__ __forceinline__ int f_off(int t, int k) {
  return ((t >> 6) * 32768) + ((k >> 5) * 2048) + ((t & 63) * 32) + (k & 31);
}
// U/W: [lb = l>>7][p = k>>5][l&127][k&31]  (64 KB per l-block)
__device__ __forceinline__ int w_off(int l, int k) {
  return ((l >> 7) * 65536) + ((k >> 5) * 4096) + ((l & 127) * 32) + (k & 31);
}

// ---------------- prep: embed gather + zero halo, cast to bf16 ----------------
__global__ __launch_bounds__(256) void k_embed(const int* __restrict__ ids,
                                               const float* __restrict__ emb,
                                               unsigned short* __restrict__ xpad) {
  int gid = blockIdx.x * 256 + threadIdx.x;
  int row = gid >> 6;
  int e4 = (gid & 63) << 2;
  int b = row / TP_;
  int tp = row - b * TP_;
  float4 v = make_float4(0.f, 0.f, 0.f, 0.f);
  if (tp >= PAD_ && tp < T_ + PAD_) {
    int id = ids[b * T_ + tp - PAD_];
    v = *(const float4*)(emb + (size_t)id * E_ + e4);
  }
  ushort4 o;
  o.x = f2bf(v.x); o.y = f2bf(v.y); o.z = f2bf(v.z); o.w = f2bf(v.w);
  *(ushort4*)(xpad + (size_t)row * E_ + e4) = o;
}

// ---------------- prep: conv_w [K,E,KS] -> W_t [K][j*256+e] bf16 ----------------
__global__ __launch_bounds__(256) void k_wt(const float* __restrict__ conv_w,
                                            unsigned short* __restrict__ wt) {
  int kk = blockIdx.x * 256 + threadIdx.x;
  int k = blockIdx.y;
  int j = kk >> 8, e = kk & 255;
  wt[(size_t)k * KK_ + kk] = f2bf(conv_w[(k * E_ + e) * KS_ + j]);
}

// ---------------- prep: U_w / final_w fp32 -> fp8 (x16), pair-unit-major ----------------
__global__ __launch_bounds__(256) void k_cast(const float* __restrict__ U_w,
                                              const float* __restrict__ F_w,
                                              unsigned char* __restrict__ u8,
                                              unsigned char* __restrict__ f8) {
  int gid = blockIdx.x * 256 + threadIdx.x;
  const float* src = blockIdx.y ? F_w : U_w;
  unsigned char* dst = blockIdx.y ? f8 : u8;
  int l = gid >> 6;
  int k0 = (gid & 63) << 3;
  const float* s = src + (size_t)l * K_ + k0;
  float4 v0 = *(const float4*)(s);
  float4 v1 = *(const float4*)(s + 4);
  uint2 o;
  o.x = pk4_fp8(v0.x * W_SCALE, v0.y * W_SCALE, v0.z * W_SCALE, v0.w * W_SCALE);
  o.y = pk4_fp8(v1.x * W_SCALE, v1.y * W_SCALE, v1.z * W_SCALE, v1.w * W_SCALE);
  *(uint2*)(dst + w_off(l, k0)) = o;
}

// ---------------- conv1d as MFMA GEMM (bf16 in, fp8 out x64, pair-unit-major) ----------------
__global__ __launch_bounds__(512, 4) void k_conv(const unsigned short* __restrict__ xpad,
                                                 const unsigned short* __restrict__ wt,
                                                 const float* __restrict__ conv_b,
                                                 unsigned char* __restrict__ feats) {
  __shared__ char At[2][16384];
  __shared__ char Bt[2][16384];
  const int tid = threadIdx.x;
  const int lane = tid & 63;
  const int q = lane >> 4, c = lane & 15;
  const int w = tid >> 6;
  const int wi = w >> 1, wj = w & 1;
  const int b = blockIdx.z;
  const int t0 = blockIdx.y * 128;
  const int n0 = blockIdx.x * 128;

  const char* xb = (const char*)(xpad + (size_t)b * TP_ * E_);
  const char* wb = (const char*)wt;

  const char* asrc[2]; const char* bsrc[2]; int ldso[2];
#pragma unroll
  for (int rnd = 0; rnd < 2; ++rnd) {
    int u = rnd * 512 + tid;
    int r = u >> 3;
    int j = (u & 7) ^ (r & 7);
    asrc[rnd] = xb + (size_t)(t0 + r) * 512 + j * 16;
    bsrc[rnd] = wb + (size_t)(n0 + r) * (KK_ * 2) + j * 16;
    ldso[rnd] = u * 16;
  }

  int offA[2][2], offB[4][2];
#pragma unroll
  for (int li = 0; li < 2; ++li) {
    int r = wi * 32 + li * 16 + c;
#pragma unroll
    for (int h = 0; h < 2; ++h) offA[li][h] = r * 128 + (((4 * h + q) ^ (r & 7)) << 4);
  }
#pragma unroll
  for (int ti = 0; ti < 4; ++ti) {
    int r = wj * 64 + ti * 16 + c;
#pragma unroll
    for (int h = 0; h < 2; ++h) offB[ti][h] = r * 128 + (((4 * h + q) ^ (r & 7)) << 4);
  }

  f32x4 acc[2][4];
  f32x4 zero = {0.f, 0.f, 0.f, 0.f};
#pragma unroll
  for (int i = 0; i < 2; ++i)
#pragma unroll
    for (int j = 0; j < 4; ++j) acc[i][j] = zero;

#pragma unroll
  for (int rnd = 0; rnd < 2; ++rnd) {
    gld_lds16(asrc[rnd], At[0] + ldso[rnd]);
    gld_lds16(bsrc[rnd], Bt[0] + ldso[rnd]);
  }

  for (int it = 0; it < 36; ++it) {
    const int bsel = it & 1;
    __syncthreads();
    if (it != 35) {
      const int kkc = (it + 1) * 64;
      const int aofs = (kkc >> 8) * 512 + (kkc & 255) * 2;
      const int bofs = kkc * 2;
#pragma unroll
      for (int rnd = 0; rnd < 2; ++rnd) {
        gld_lds16(asrc[rnd] + aofs, At[bsel ^ 1] + ldso[rnd]);
        gld_lds16(bsrc[rnd] + bofs, Bt[bsel ^ 1] + ldso[rnd]);
      }
    }
    const char* aB = At[bsel];
    const char* bB = Bt[bsel];
#pragma unroll
    for (int h = 0; h < 2; ++h) {
      bf16x8 afr[2], bfr[4];
#pragma unroll
      for (int li = 0; li < 2; ++li) afr[li] = *(const bf16x8*)(aB + offA[li][h]);
#pragma unroll
      for (int ti = 0; ti < 4; ++ti) bfr[ti] = *(const bf16x8*)(bB + offB[ti][h]);
#pragma unroll
      for (int ti = 0; ti < 4; ++ti)
#pragma unroll
        for (int li = 0; li < 2; ++li)
          acc[li][ti] = mfma_bf16(afr[li], bfr[ti], acc[li][ti]);
    }
  }

  // epilogue: +bias, relu, fp8 store into the pair-unit-major feats layout.
  const size_t fbase = (size_t)b * T_ * K_;
#pragma unroll
  for (int ti = 0; ti < 4; ++ti) {
    int k = n0 + wj * 64 + ti * 16 + c;
    float bias = conv_b[k];
#pragma unroll
    for (int li = 0; li < 2; ++li) {
      int tb = t0 + wi * 32 + li * 16 + q * 4;
#pragma unroll
      for (int rr = 0; rr < 4; ++rr) {
        float v = fmaxf(acc[li][ti][rr] + bias, 0.f) * FEAT_SCALE;
        int t = tb + rr;
        feats[fbase + f_off(t, k)] = f2fp8(v);
      }
    }
  }
}

// ---------------- fused label-attention ----------------
// 512 threads = 8 waves (4 L-quarters x 2 T-halves), MX-scaled MFMA 32x32x64.
// R3 double-buffer + __syncthreads (the R4 vmcnt-ring regressed: drain was
// never the bottleneck). New: PING-PONG accumulators — the softmax of chunk
// tc-1 is interleaved between chunk tc's MFMAs, so it executes in the MFMA
// shadow instead of serializing before the barrier (R3: MFMA 48% + VALU 37%
// ran in-phase, additive). Statically unrolled x2 (no runtime acc indexing).
__global__ __launch_bounds__(512, 2) void k_attn(const unsigned char* __restrict__ feats,
                                                 const unsigned char* __restrict__ u8,
                                                 const unsigned char* __restrict__ f8,
                                                 const float* __restrict__ final_b,
                                                 float* __restrict__ out) {
  __shared__ __align__(64) char smem[131072];
  __shared__ float red[512];
  const int tid = threadIdx.x;
  const int lane = tid & 63;
  const int q2 = lane >> 5, c32 = lane & 31;
  const int w = tid >> 6;
  const int wi = w >> 1;   // L quarter (32 rows)
  const int wj = w & 1;    // T half (32 cols of the 64-col chunk)
  const int b = blockIdx.y;
  const int l0 = blockIdx.x * 128;

  const unsigned char* fb = feats + (size_t)b * T_ * K_;

  // ---- stage U/W (pair-unit-major) identity into LDS: 64 KB each ----
  char* Us = smem;
  char* Ws = smem + 65536;
#pragma unroll
  for (int rr = 0; rr < 8; ++rr) {
    gld_lds16(u8 + (size_t)l0 * K_ + rr * 8192 + tid * 16, Us + rr * 8192 + tid * 16);
    gld_lds16(f8 + (size_t)l0 * K_ + rr * 8192 + tid * 16, Ws + rr * 8192 + tid * 16);
  }
  __syncthreads();

  // ---- pull full-K A-fragments into registers: 8 x 32B contiguous ----
  // Layout [p][128][32]: lane row arow needs pair p = s*2+q2 at p*4096+arow*32.
  const int arow = wi * 32 + c32;
  i32x8 uf[8], wf[8];
#pragma unroll
  for (int s = 0; s < 8; ++s) {
    int off = (s * 2 + q2) * 4096 + arow * 32;
    uf[s] = *(const i32x8*)(Us + off);
    wf[s] = *(const i32x8*)(Ws + off);
  }
  __syncthreads();   // all waves done reading before F overwrites this region

  // ---- F double-buffer in the same LDS: 2 x 32 KB ([p][64][32] per chunk) ----
  char* const Fs0 = smem;
  char* const Fs1 = smem + 32768;
  const unsigned char* fsrc = fb + tid * 16;   // + tc*32768 + rr*8192
#pragma unroll
  for (int rr = 0; rr < 4; ++rr)
    gld_lds16(fsrc + rr * 8192, Fs0 + tid * 16 + rr * 8192);

  // Layout [p][64][32]: lane row brow, pair p = s*2+q2 -> bbase + s*4096.
  const int brow = wj * 32 + c32;
  const int bbase = q2 * 2048 + brow * 32;

  f32x16 sA, vA, sB, vB;
  float num[16], den[16];
#pragma unroll
  for (int r = 0; r < 16; ++r) { num[r] = 0.f; den[r] = 0.f; }

// softmax step for one element of the PREVIOUS chunk's accumulators
#define SM1(PS, PV, rr_)                                         \
  {                                                              \
    float p_ = __builtin_exp2f(PS[rr_] * INV_SS_LOG2E);          \
    den[rr_] += p_;                                              \
    num[rr_] += p_ * PV[rr_];                                    \
  }

// one chunk: MFMA into (CS,CV) from buffer BUF, softmax prev (PS,PV) if DO_SM
#define CHUNK_BODY(BUF, CS, CV, PS, PV, DO_SM)                   \
  {                                                              \
    _Pragma("unroll")                                            \
    for (int r = 0; r < 16; ++r) { CS[r] = 0.f; CV[r] = 0.f; }   \
    _Pragma("unroll")                                            \
    for (int s = 0; s < 8; ++s) {                                \
      i32x8 fa = *(const i32x8*)(BUF + bbase + s * 4096);        \
      CS = mfma_sc64(uf[s], fa, CS);                             \
      CV = mfma_sc64(wf[s], fa, CV);                             \
      if (DO_SM) { SM1(PS, PV, 2 * s) SM1(PS, PV, 2 * s + 1) }   \
    }                                                            \
  }

  // chunk 0: into A, no softmax yet
  __syncthreads();
#pragma unroll
  for (int rr = 0; rr < 4; ++rr)
    gld_lds16(fsrc + 32768 + rr * 8192, Fs1 + tid * 16 + rr * 8192);
  CHUNK_BODY(Fs0, sA, vA, sB, vB, false)

  for (int tc = 1; tc < 31; tc += 2) {
    // odd chunk tc: read Fs1, compute into B, softmax A
    __syncthreads();
    {
      const unsigned char* nsrc = fsrc + (tc + 1) * 32768;
#pragma unroll
      for (int rr = 0; rr < 4; ++rr)
        gld_lds16(nsrc + rr * 8192, Fs0 + tid * 16 + rr * 8192);
    }
    CHUNK_BODY(Fs1, sB, vB, sA, vA, true)
    // even chunk tc+1: read Fs0, compute into A, softmax B
    __syncthreads();
    {
      const unsigned char* nsrc = fsrc + (tc + 2) * 32768;
#pragma unroll
      for (int rr = 0; rr < 4; ++rr)
        gld_lds16(nsrc + rr * 8192, Fs1 + tid * 16 + rr * 8192);
    }
    CHUNK_BODY(Fs0, sA, vA, sB, vB, true)
  }

  // chunk 31: read Fs1, compute into B, softmax A; no prefetch
  __syncthreads();
  CHUNK_BODY(Fs1, sB, vB, sA, vA, true)
  // final softmax for chunk 31's set
#pragma unroll
  for (int r = 0; r < 16; ++r) SM1(sB, vB, r)

#undef CHUNK_BODY
#undef SM1

  // reduce over 32 t-columns (c32 lanes; q2 halves hold different L-rows)
#pragma unroll
  for (int r = 0; r < 16; ++r) {
#pragma unroll
    for (int m = 1; m < 32; m <<= 1) {
      num[r] += __shfl_xor(num[r], m, 64);
      den[r] += __shfl_xor(den[r], m, 64);
    }
  }
  if (c32 == 0) {
#pragma unroll
    for (int r = 0; r < 16; ++r) {
      // C/D 32x32: row = (reg&3) + 8*(reg>>2) + 4*(lane>>5)
      int ll = wi * 32 + (r & 3) + 8 * (r >> 2) + 4 * q2;
      red[wj * 256 + ll] = num[r];
      red[wj * 256 + 128 + ll] = den[r];
    }
  }
  __syncthreads();
  if (tid < 128) {
    int l = l0 + tid;
    float n = red[tid] + red[256 + tid];
    float d = red[128 + tid] + red[384 + tid];
    out[(size_t)b * L_ + l] = (n * INV_SS) / d + final_b[l];
  }
}

// ---------------- BCE-with-logits mean ----------------
__global__ __launch_bounds__(256) void k_loss(const float* __restrict__ yhat,
                                              const float* __restrict__ target,
                                              float* __restrict__ loss) {
  int gid = blockIdx.x * 256 + threadIdx.x;
  float s = 0.f;
  for (int i = gid; i < B_ * L_; i += 64 * 256) {
    float y = yhat[i], t = target[i];
    s += fmaxf(y, 0.f) - y * t + log1pf(__expf(-fabsf(y)));
  }
#pragma unroll
  for (int m = 1; m < 64; m <<= 1) s += __shfl_xor(s, m, 64);
  if ((threadIdx.x & 63) == 0) atomicAdd(loss, s * (1.0f / (B_ * L_)));
}

extern "C" void kernel_launch(void* const* d_in, const int* in_sizes, int n_in,
                              void* d_out, int out_size, void* d_ws, size_t ws_size,
                              hipStream_t stream) {
  const int* ids = (const int*)d_in[0];
  const float* target = (const float*)d_in[3];
  const float* emb = (const float*)d_in[4];
  const float* conv_w = (const float*)d_in[5];
  const float* conv_b = (const float*)d_in[6];
  const float* U_w = (const float*)d_in[7];
  const float* F_w = (const float*)d_in[8];
  const float* final_b = (const float*)d_in[9];
  float* out = (float*)d_out;

  char* ws = (char*)d_ws;
  unsigned short* xpad = (unsigned short*)ws;                    // bf16 B*TP*E
  size_t off = (size_t)B_ * TP_ * E_ * 2;
  unsigned short* wt = (unsigned short*)(ws + off);              // bf16 K*KK
  off += (size_t)K_ * KK_ * 2;
  unsigned char* u8 = (unsigned char*)(ws + off);                // fp8 L*K (unit-major)
  off += (size_t)L_ * K_;
  unsigned char* f8 = (unsigned char*)(ws + off);                // fp8 L*K (unit-major)
  off += (size_t)L_ * K_;
  unsigned char* feats = (unsigned char*)(ws + off);             // fp8 B*T*K (unit-major)
  off += (size_t)B_ * T_ * K_;
  if (ws_size < off) return;

  k_embed<<<dim3((B_ * TP_ * 64) / 256), 256, 0, stream>>>(ids, emb, xpad);
  k_wt<<<dim3(KK_ / 256, K_), 256, 0, stream>>>(conv_w, wt);
  k_cast<<<dim3((L_ * K_ / 8) / 256, 2), 256, 0, stream>>>(U_w, F_w, u8, f8);
  k_conv<<<dim3(K_ / 128, T_ / 128, B_), 512, 0, stream>>>(xpad, wt, conv_b, feats);
  k_attn<<<dim3(L_ / 128, B_), 512, 0, stream>>>(feats, u8, f8, final_b, out);
  hipMemsetAsync(out + B_ * L_, 0, sizeof(float), stream);
  k_loss<<<dim3(64), 256, 0, stream>>>(out, target, out + B_ * L_);
}

// Round 6
// 349.817 us; speedup vs baseline: 1.4687x; 1.4687x over previous
//
#include <hip/hip_runtime.h>
#include <hip/hip_bf16.h>
#include <cstdint>

#define B_ 8
#define T_ 2048
#define E_ 256
#define K_ 512
#define KS_ 9
#define L_ 8192
#define PAD_ 4
#define TP_ (T_ + 2 * PAD_)   // 2056
#define KK_ (E_ * KS_)        // 2304

// fp8 scaling: feats stored as fp8*64, U/final stored as fp8*16.
// S and V accumulators are 1024x true value -> multiply by 2^-10 in epilogue.
#define FEAT_SCALE 64.0f
#define W_SCALE 16.0f
#define INV_SS 9.765625e-4f         // 2^-10
#define INV_SS_LOG2E 1.40888719e-3f // 2^-10 * log2(e)

typedef __bf16 bf16x8 __attribute__((ext_vector_type(8)));
typedef float f32x4 __attribute__((ext_vector_type(4)));
typedef float f32x16 __attribute__((ext_vector_type(16)));
typedef int i32x4 __attribute__((ext_vector_type(4)));
typedef int i32x8 __attribute__((ext_vector_type(8)));

__device__ __forceinline__ unsigned short f2bf(float f) {
  union { float f; unsigned int u; } a; a.f = f;
  unsigned int r = (a.u + 0x7FFFu + ((a.u >> 16) & 1u)) >> 16;
  return (unsigned short)r;
}

__device__ __forceinline__ unsigned char f2fp8(float v) {
  return (unsigned char)(__builtin_amdgcn_cvt_pk_fp8_f32(v, v, 0, false) & 0xFF);
}

__device__ __forceinline__ unsigned int pk4_fp8(float a, float b, float c, float d) {
  int v = __builtin_amdgcn_cvt_pk_fp8_f32(a, b, 0, false);
  v = __builtin_amdgcn_cvt_pk_fp8_f32(c, d, v, true);
  return (unsigned int)v;
}

__device__ __forceinline__ void gld_lds16(const void* g, void* l) {
  __builtin_amdgcn_global_load_lds(
      (const __attribute__((address_space(1))) unsigned int*)g,
      (__attribute__((address_space(3))) unsigned int*)l, 16, 0, 0);
}

__device__ __forceinline__ f32x4 mfma_bf16(bf16x8 a, bf16x8 b, f32x4 c) {
  return __builtin_amdgcn_mfma_f32_16x16x32_bf16(a, b, c, 0, 0, 0);
}

// MX-scaled fp8 MFMA, K=64, unity e8m0 scales (0x7F -> 2^0). 2x non-scaled rate.
__device__ __forceinline__ f32x16 mfma_sc64(i32x8 a, i32x8 b, f32x16 c) {
  return __builtin_amdgcn_mfma_scale_f32_32x32x64_f8f6f4(a, b, c, 0, 0, 0, 127, 0, 127);
}

// K-unit-major (16B) layouts — the HW-verified conflict-free pattern (R3:
// SQ_LDS_BANK_CONFLICT 8.9M -> 0). Fragment reads: 32 lanes x 16B contiguous
// (512 B per half-wave). The R5 32B-stride variant reintroduced 8.9M
// conflicts (lane step 32B -> only 4 of 8 16B-windows per 128B bank wrap).
// feats per batch: [tc = t>>6][u = k>>4][t&63][k&15]  (32 KB per t-chunk)
__device__ __forceinline__ int f_off(int t, int k) {
  return ((t >> 6) * 32768) + (((k >> 4) * 64 + (t & 63)) << 4) + (k & 15);
}
// U/W: [lb = l>>7][u = k>>4][l&127][k&15]  (64 KB per l-block)
__device__ __forceinline__ int w_off(int l, int k) {
  return ((l >> 7) * 65536) + (((k >> 4) * 128 + (l & 127)) << 4) + (k & 15);
}

// ---------------- prep: embed gather + zero halo, cast to bf16 ----------------
__global__ __launch_bounds__(256) void k_embed(const int* __restrict__ ids,
                                               const float* __restrict__ emb,
                                               unsigned short* __restrict__ xpad) {
  int gid = blockIdx.x * 256 + threadIdx.x;
  int row = gid >> 6;
  int e4 = (gid & 63) << 2;
  int b = row / TP_;
  int tp = row - b * TP_;
  float4 v = make_float4(0.f, 0.f, 0.f, 0.f);
  if (tp >= PAD_ && tp < T_ + PAD_) {
    int id = ids[b * T_ + tp - PAD_];
    v = *(const float4*)(emb + (size_t)id * E_ + e4);
  }
  ushort4 o;
  o.x = f2bf(v.x); o.y = f2bf(v.y); o.z = f2bf(v.z); o.w = f2bf(v.w);
  *(ushort4*)(xpad + (size_t)row * E_ + e4) = o;
}

// ---------------- prep: conv_w [K,E,KS] -> W_t [K][j*256+e] bf16 ----------------
__global__ __launch_bounds__(256) void k_wt(const float* __restrict__ conv_w,
                                            unsigned short* __restrict__ wt) {
  int kk = blockIdx.x * 256 + threadIdx.x;
  int k = blockIdx.y;
  int j = kk >> 8, e = kk & 255;
  wt[(size_t)k * KK_ + kk] = f2bf(conv_w[(k * E_ + e) * KS_ + j]);
}

// ---------------- prep: U_w / final_w fp32 -> fp8 (x16), K-unit-major ----------------
__global__ __launch_bounds__(256) void k_cast(const float* __restrict__ U_w,
                                              const float* __restrict__ F_w,
                                              unsigned char* __restrict__ u8,
                                              unsigned char* __restrict__ f8) {
  int gid = blockIdx.x * 256 + threadIdx.x;
  const float* src = blockIdx.y ? F_w : U_w;
  unsigned char* dst = blockIdx.y ? f8 : u8;
  int l = gid >> 6;
  int k0 = (gid & 63) << 3;
  const float* s = src + (size_t)l * K_ + k0;
  float4 v0 = *(const float4*)(s);
  float4 v1 = *(const float4*)(s + 4);
  uint2 o;
  o.x = pk4_fp8(v0.x * W_SCALE, v0.y * W_SCALE, v0.z * W_SCALE, v0.w * W_SCALE);
  o.y = pk4_fp8(v1.x * W_SCALE, v1.y * W_SCALE, v1.z * W_SCALE, v1.w * W_SCALE);
  *(uint2*)(dst + w_off(l, k0)) = o;
}

// ---------------- conv1d as MFMA GEMM (bf16 in, fp8 out x64, K-unit-major) ----------------
__global__ __launch_bounds__(512, 4) void k_conv(const unsigned short* __restrict__ xpad,
                                                 const unsigned short* __restrict__ wt,
                                                 const float* __restrict__ conv_b,
                                                 unsigned char* __restrict__ feats) {
  __shared__ char At[2][16384];
  __shared__ char Bt[2][16384];
  const int tid = threadIdx.x;
  const int lane = tid & 63;
  const int q = lane >> 4, c = lane & 15;
  const int w = tid >> 6;
  const int wi = w >> 1, wj = w & 1;
  const int b = blockIdx.z;
  const int t0 = blockIdx.y * 128;
  const int n0 = blockIdx.x * 128;

  const char* xb = (const char*)(xpad + (size_t)b * TP_ * E_);
  const char* wb = (const char*)wt;

  const char* asrc[2]; const char* bsrc[2]; int ldso[2];
#pragma unroll
  for (int rnd = 0; rnd < 2; ++rnd) {
    int u = rnd * 512 + tid;
    int r = u >> 3;
    int j = (u & 7) ^ (r & 7);
    asrc[rnd] = xb + (size_t)(t0 + r) * 512 + j * 16;
    bsrc[rnd] = wb + (size_t)(n0 + r) * (KK_ * 2) + j * 16;
    ldso[rnd] = u * 16;
  }

  int offA[2][2], offB[4][2];
#pragma unroll
  for (int li = 0; li < 2; ++li) {
    int r = wi * 32 + li * 16 + c;
#pragma unroll
    for (int h = 0; h < 2; ++h) offA[li][h] = r * 128 + (((4 * h + q) ^ (r & 7)) << 4);
  }
#pragma unroll
  for (int ti = 0; ti < 4; ++ti) {
    int r = wj * 64 + ti * 16 + c;
#pragma unroll
    for (int h = 0; h < 2; ++h) offB[ti][h] = r * 128 + (((4 * h + q) ^ (r & 7)) << 4);
  }

  f32x4 acc[2][4];
  f32x4 zero = {0.f, 0.f, 0.f, 0.f};
#pragma unroll
  for (int i = 0; i < 2; ++i)
#pragma unroll
    for (int j = 0; j < 4; ++j) acc[i][j] = zero;

#pragma unroll
  for (int rnd = 0; rnd < 2; ++rnd) {
    gld_lds16(asrc[rnd], At[0] + ldso[rnd]);
    gld_lds16(bsrc[rnd], Bt[0] + ldso[rnd]);
  }

  for (int it = 0; it < 36; ++it) {
    const int bsel = it & 1;
    __syncthreads();
    if (it != 35) {
      const int kkc = (it + 1) * 64;
      const int aofs = (kkc >> 8) * 512 + (kkc & 255) * 2;
      const int bofs = kkc * 2;
#pragma unroll
      for (int rnd = 0; rnd < 2; ++rnd) {
        gld_lds16(asrc[rnd] + aofs, At[bsel ^ 1] + ldso[rnd]);
        gld_lds16(bsrc[rnd] + bofs, Bt[bsel ^ 1] + ldso[rnd]);
      }
    }
    const char* aB = At[bsel];
    const char* bB = Bt[bsel];
#pragma unroll
    for (int h = 0; h < 2; ++h) {
      bf16x8 afr[2], bfr[4];
#pragma unroll
      for (int li = 0; li < 2; ++li) afr[li] = *(const bf16x8*)(aB + offA[li][h]);
#pragma unroll
      for (int ti = 0; ti < 4; ++ti) bfr[ti] = *(const bf16x8*)(bB + offB[ti][h]);
#pragma unroll
      for (int ti = 0; ti < 4; ++ti)
#pragma unroll
        for (int li = 0; li < 2; ++li)
          acc[li][ti] = mfma_bf16(afr[li], bfr[ti], acc[li][ti]);
    }
  }

  // epilogue: +bias, relu, fp8 store into the K-unit-major feats layout.
  const size_t fbase = (size_t)b * T_ * K_;
#pragma unroll
  for (int ti = 0; ti < 4; ++ti) {
    int k = n0 + wj * 64 + ti * 16 + c;
    float bias = conv_b[k];
#pragma unroll
    for (int li = 0; li < 2; ++li) {
      int tb = t0 + wi * 32 + li * 16 + q * 4;
#pragma unroll
      for (int rr = 0; rr < 4; ++rr) {
        float v = fmaxf(acc[li][ti][rr] + bias, 0.f) * FEAT_SCALE;
        int t = tb + rr;
        feats[fbase + f_off(t, k)] = f2fp8(v);
      }
    }
  }
}

// ---------------- fused label-attention ----------------
// R3 structure (K-unit-major LDS, dbuf + __syncthreads — 124 µs verified,
// 0 bank conflicts) + ping-pong accumulators funded by REGISTER REBALANCE:
// U stays in the LDS half that the F double-buffer does NOT overwrite
// (bytes 64K..128K) and its fragments are re-read per chunk (16 extra
// conflict-free ds_read_b128/wave/chunk, LDS pipe has 3x headroom vs the
// 2200-cyc MFMA phase); W frags live in regs (64). Freed 64 VGPRs fund the
// second acc set, so the softmax of chunk tc-1 interleaves between chunk
// tc's MFMAs and runs in the MFMA shadow (R5's version of this spilled:
// FETCH 41->700 MB at ~250 live regs; now ~200).
__global__ __launch_bounds__(512, 2) void k_attn(const unsigned char* __restrict__ feats,
                                                 const unsigned char* __restrict__ u8,
                                                 const unsigned char* __restrict__ f8,
                                                 const float* __restrict__ final_b,
                                                 float* __restrict__ out) {
  __shared__ __align__(16) char smem[131072];
  __shared__ float red[512];
  const int tid = threadIdx.x;
  const int lane = tid & 63;
  const int q2 = lane >> 5, c32 = lane & 31;
  const int w = tid >> 6;
  const int wi = w >> 1;   // L quarter (32 rows)
  const int wj = w & 1;    // T half (32 cols of the 64-col chunk)
  const int b = blockIdx.y;
  const int l0 = blockIdx.x * 128;

  const unsigned char* fb = feats + (size_t)b * T_ * K_;

  // ---- stage: W -> smem[0,64K) (regs, then overwritten); U -> smem[64K,128K) (persistent) ----
  char* Ws = smem;
  char* Us = smem + 65536;
#pragma unroll
  for (int rr = 0; rr < 8; ++rr) {
    gld_lds16(f8 + (size_t)l0 * K_ + rr * 8192 + tid * 16, Ws + rr * 8192 + tid * 16);
    gld_lds16(u8 + (size_t)l0 * K_ + rr * 8192 + tid * 16, Us + rr * 8192 + tid * 16);
  }
  __syncthreads();

  // ---- W fragments into registers: 8 K-blocks x 32B each ----
  // Layout [u][128][16]: unit u at u*2048 + l_local*16. Lane needs units
  // u = s*4 + q2*2 + {0,1}  ->  base + s*8192 + {0,2048}.
  const int arow = wi * 32 + c32;
  const int abase = q2 * 4096 + arow * 16;
  i32x8 wf[8];
#pragma unroll
  for (int s = 0; s < 8; ++s) {
    int o0 = abase + s * 8192;
    i32x4 wl = *(const i32x4*)(Ws + o0);
    i32x4 wh = *(const i32x4*)(Ws + o0 + 2048);
    wf[s] = __builtin_shufflevector(wl, wh, 0, 1, 2, 3, 4, 5, 6, 7);
  }
  __syncthreads();   // all waves done reading W before the F dbuf overwrites it

  // ---- F double-buffer in smem[0,64K): 2 x 32 KB ([u][64][16] per chunk) ----
  char* const Fs0 = smem;
  char* const Fs1 = smem + 32768;
  const unsigned char* fsrc = fb + tid * 16;   // + tc*32768 + rr*8192
#pragma unroll
  for (int rr = 0; rr < 4; ++rr)
    gld_lds16(fsrc + rr * 8192, Fs0 + tid * 16 + rr * 8192);

  // Layout [u][64][16]: unit u at u*1024 + t_local*16. Lane needs units
  // u = s*4 + q2*2 + {0,1}  ->  bbase + s*4096 + {0,1024}.
  const int brow = wj * 32 + c32;
  const int bbase = q2 * 2048 + brow * 16;

  f32x16 sA, vA, sB, vB;
  float num[16], den[16];
#pragma unroll
  for (int r = 0; r < 16; ++r) { num[r] = 0.f; den[r] = 0.f; }

// softmax step for one element of the PREVIOUS chunk's accumulators
#define SM1(PS, PV, rr_)                                         \
  {                                                              \
    float p_ = __builtin_exp2f(PS[rr_] * INV_SS_LOG2E);          \
    den[rr_] += p_;                                              \
    num[rr_] += p_ * PV[rr_];                                    \
  }

// one chunk: MFMA into (CS,CV) from buffer BUF (U frags re-read from the
// persistent LDS region), softmax prev (PS,PV) interleaved if DO_SM.
#define CHUNK_BODY(BUF, CS, CV, PS, PV, DO_SM)                        \
  {                                                                   \
    _Pragma("unroll")                                                 \
    for (int r = 0; r < 16; ++r) { CS[r] = 0.f; CV[r] = 0.f; }        \
    _Pragma("unroll")                                                 \
    for (int s = 0; s < 8; ++s) {                                     \
      i32x4 flo = *(const i32x4*)(BUF + bbase + s * 4096);            \
      i32x4 fhi = *(const i32x4*)(BUF + bbase + s * 4096 + 1024);     \
      i32x8 fa = __builtin_shufflevector(flo, fhi, 0, 1, 2, 3, 4, 5, 6, 7); \
      i32x4 ulo = *(const i32x4*)(Us + abase + s * 8192);             \
      i32x4 uhi = *(const i32x4*)(Us + abase + s * 8192 + 2048);      \
      i32x8 ua = __builtin_shufflevector(ulo, uhi, 0, 1, 2, 3, 4, 5, 6, 7); \
      CS = mfma_sc64(ua, fa, CS);                                     \
      CV = mfma_sc64(wf[s], fa, CV);                                  \
      if (DO_SM) { SM1(PS, PV, 2 * s) SM1(PS, PV, 2 * s + 1) }        \
    }                                                                 \
  }

  // chunk 0: into A, no softmax yet
  __syncthreads();
#pragma unroll
  for (int rr = 0; rr < 4; ++rr)
    gld_lds16(fsrc + 32768 + rr * 8192, Fs1 + tid * 16 + rr * 8192);
  CHUNK_BODY(Fs0, sA, vA, sB, vB, false)

  for (int tc = 1; tc < 31; tc += 2) {
    // odd chunk tc: read Fs1, compute into B, softmax A
    __syncthreads();
    {
      const unsigned char* nsrc = fsrc + (size_t)(tc + 1) * 32768;
#pragma unroll
      for (int rr = 0; rr < 4; ++rr)
        gld_lds16(nsrc + rr * 8192, Fs0 + tid * 16 + rr * 8192);
    }
    CHUNK_BODY(Fs1, sB, vB, sA, vA, true)
    // even chunk tc+1: read Fs0, compute into A, softmax B
    __syncthreads();
    {
      const unsigned char* nsrc = fsrc + (size_t)(tc + 2) * 32768;
#pragma unroll
      for (int rr = 0; rr < 4; ++rr)
        gld_lds16(nsrc + rr * 8192, Fs1 + tid * 16 + rr * 8192);
    }
    CHUNK_BODY(Fs0, sA, vA, sB, vB, true)
  }

  // chunk 31: read Fs1, compute into B, softmax A; no prefetch
  __syncthreads();
  CHUNK_BODY(Fs1, sB, vB, sA, vA, true)
  // final softmax for chunk 31's set
#pragma unroll
  for (int r = 0; r < 16; ++r) SM1(sB, vB, r)

#undef CHUNK_BODY
#undef SM1

  // reduce over 32 t-columns (c32 lanes; q2 halves hold different L-rows)
#pragma unroll
  for (int r = 0; r < 16; ++r) {
#pragma unroll
    for (int m = 1; m < 32; m <<= 1) {
      num[r] += __shfl_xor(num[r], m, 64);
      den[r] += __shfl_xor(den[r], m, 64);
    }
  }
  if (c32 == 0) {
#pragma unroll
    for (int r = 0; r < 16; ++r) {
      // C/D 32x32: row = (reg&3) + 8*(reg>>2) + 4*(lane>>5)
      int ll = wi * 32 + (r & 3) + 8 * (r >> 2) + 4 * q2;
      red[wj * 256 + ll] = num[r];
      red[wj * 256 + 128 + ll] = den[r];
    }
  }
  __syncthreads();
  if (tid < 128) {
    int l = l0 + tid;
    float n = red[tid] + red[256 + tid];
    float d = red[128 + tid] + red[384 + tid];
    out[(size_t)b * L_ + l] = (n * INV_SS) / d + final_b[l];
  }
}

// ---------------- BCE-with-logits mean ----------------
__global__ __launch_bounds__(256) void k_loss(const float* __restrict__ yhat,
                                              const float* __restrict__ target,
                                              float* __restrict__ loss) {
  int gid = blockIdx.x * 256 + threadIdx.x;
  float s = 0.f;
  for (int i = gid; i < B_ * L_; i += 64 * 256) {
    float y = yhat[i], t = target[i];
    s += fmaxf(y, 0.f) - y * t + log1pf(__expf(-fabsf(y)));
  }
#pragma unroll
  for (int m = 1; m < 64; m <<= 1) s += __shfl_xor(s, m, 64);
  if ((threadIdx.x & 63) == 0) atomicAdd(loss, s * (1.0f / (B_ * L_)));
}

extern "C" void kernel_launch(void* const* d_in, const int* in_sizes, int n_in,
                              void* d_out, int out_size, void* d_ws, size_t ws_size,
                              hipStream_t stream) {
  const int* ids = (const int*)d_in[0];
  const float* target = (const float*)d_in[3];
  const float* emb = (const float*)d_in[4];
  const float* conv_w = (const float*)d_in[5];
  const float* conv_b = (const float*)d_in[6];
  const float* U_w = (const float*)d_in[7];
  const float* F_w = (const float*)d_in[8];
  const float* final_b = (const float*)d_in[9];
  float* out = (float*)d_out;

  char* ws = (char*)d_ws;
  unsigned short* xpad = (unsigned short*)ws;                    // bf16 B*TP*E
  size_t off = (size_t)B_ * TP_ * E_ * 2;
  unsigned short* wt = (unsigned short*)(ws + off);              // bf16 K*KK
  off += (size_t)K_ * KK_ * 2;
  unsigned char* u8 = (unsigned char*)(ws + off);                // fp8 L*K (unit-major)
  off += (size_t)L_ * K_;
  unsigned char* f8 = (unsigned char*)(ws + off);                // fp8 L*K (unit-major)
  off += (size_t)L_ * K_;
  unsigned char* feats = (unsigned char*)(ws + off);             // fp8 B*T*K (unit-major)
  off += (size_t)B_ * T_ * K_;
  if (ws_size < off) return;

  k_embed<<<dim3((B_ * TP_ * 64) / 256), 256, 0, stream>>>(ids, emb, xpad);
  k_wt<<<dim3(KK_ / 256, K_), 256, 0, stream>>>(conv_w, wt);
  k_cast<<<dim3((L_ * K_ / 8) / 256, 2), 256, 0, stream>>>(U_w, F_w, u8, f8);
  k_conv<<<dim3(K_ / 128, T_ / 128, B_), 512, 0, stream>>>(xpad, wt, conv_b, feats);
  k_attn<<<dim3(L_ / 128, B_), 512, 0, stream>>>(feats, u8, f8, final_b, out);
  hipMemsetAsync(out + B_ * L_, 0, sizeof(float), stream);
  k_loss<<<dim3(64), 256, 0, stream>>>(out, target, out + B_ * L_);
}

// Round 7
// 302.926 us; speedup vs baseline: 1.6961x; 1.1548x over previous
//
#include <hip/hip_runtime.h>
#include <hip/hip_bf16.h>
#include <cstdint>

#define B_ 8
#define T_ 2048
#define E_ 256
#define K_ 512
#define KS_ 9
#define L_ 8192
#define PAD_ 4
#define TP_ (T_ + 2 * PAD_)   // 2056
#define KK_ (E_ * KS_)        // 2304

// fp8 scaling: feats stored as fp8*64, U/final stored as fp8*16.
// S and V accumulators are 1024x true value -> multiply by 2^-10 in epilogue.
#define FEAT_SCALE 64.0f
#define W_SCALE 16.0f
#define INV_SS 9.765625e-4f         // 2^-10
#define INV_SS_LOG2E 1.40888719e-3f // 2^-10 * log2(e)

typedef __bf16 bf16x8 __attribute__((ext_vector_type(8)));
typedef float f32x4 __attribute__((ext_vector_type(4)));
typedef float f32x16 __attribute__((ext_vector_type(16)));
typedef int i32x4 __attribute__((ext_vector_type(4)));
typedef int i32x8 __attribute__((ext_vector_type(8)));

__device__ __forceinline__ unsigned short f2bf(float f) {
  union { float f; unsigned int u; } a; a.f = f;
  unsigned int r = (a.u + 0x7FFFu + ((a.u >> 16) & 1u)) >> 16;
  return (unsigned short)r;
}

__device__ __forceinline__ unsigned char f2fp8(float v) {
  return (unsigned char)(__builtin_amdgcn_cvt_pk_fp8_f32(v, v, 0, false) & 0xFF);
}

__device__ __forceinline__ unsigned int pk4_fp8(float a, float b, float c, float d) {
  int v = __builtin_amdgcn_cvt_pk_fp8_f32(a, b, 0, false);
  v = __builtin_amdgcn_cvt_pk_fp8_f32(c, d, v, true);
  return (unsigned int)v;
}

__device__ __forceinline__ void gld_lds16(const void* g, void* l) {
  __builtin_amdgcn_global_load_lds(
      (const __attribute__((address_space(1))) unsigned int*)g,
      (__attribute__((address_space(3))) unsigned int*)l, 16, 0, 0);
}

__device__ __forceinline__ f32x4 mfma_bf16(bf16x8 a, bf16x8 b, f32x4 c) {
  return __builtin_amdgcn_mfma_f32_16x16x32_bf16(a, b, c, 0, 0, 0);
}

// MX-scaled fp8 MFMA, K=64, unity e8m0 scales (0x7F -> 2^0). 2x non-scaled rate.
__device__ __forceinline__ f32x16 mfma_sc64(i32x8 a, i32x8 b, f32x16 c) {
  return __builtin_amdgcn_mfma_scale_f32_32x32x64_f8f6f4(a, b, c, 0, 0, 0, 127, 0, 127);
}

// K-unit-major (16B) layouts — the HW-verified conflict-free pattern (R3:
// SQ_LDS_BANK_CONFLICT 8.9M -> 0). Fragment reads: 32 lanes x 16B contiguous
// (512 B per half-wave). 32B-stride variants reintroduce conflicts (R5).
// feats per batch: [tc = t>>6][u = k>>4][t&63][k&15]  (32 KB per t-chunk)
__device__ __forceinline__ int f_off(int t, int k) {
  return ((t >> 6) * 32768) + (((k >> 4) * 64 + (t & 63)) << 4) + (k & 15);
}
// U/W: [lb = l>>7][u = k>>4][l&127][k&15]  (64 KB per l-block)
__device__ __forceinline__ int w_off(int l, int k) {
  return ((l >> 7) * 65536) + (((k >> 4) * 128 + (l & 127)) << 4) + (k & 15);
}

// ---------------- prep: embed gather + zero halo, cast to bf16 ----------------
__global__ __launch_bounds__(256) void k_embed(const int* __restrict__ ids,
                                               const float* __restrict__ emb,
                                               unsigned short* __restrict__ xpad) {
  int gid = blockIdx.x * 256 + threadIdx.x;
  int row = gid >> 6;
  int e4 = (gid & 63) << 2;
  int b = row / TP_;
  int tp = row - b * TP_;
  float4 v = make_float4(0.f, 0.f, 0.f, 0.f);
  if (tp >= PAD_ && tp < T_ + PAD_) {
    int id = ids[b * T_ + tp - PAD_];
    v = *(const float4*)(emb + (size_t)id * E_ + e4);
  }
  ushort4 o;
  o.x = f2bf(v.x); o.y = f2bf(v.y); o.z = f2bf(v.z); o.w = f2bf(v.w);
  *(ushort4*)(xpad + (size_t)row * E_ + e4) = o;
}

// ---------------- prep: conv_w [K,E,KS] -> W_t [K][j*256+e] bf16 ----------------
__global__ __launch_bounds__(256) void k_wt(const float* __restrict__ conv_w,
                                            unsigned short* __restrict__ wt) {
  int kk = blockIdx.x * 256 + threadIdx.x;
  int k = blockIdx.y;
  int j = kk >> 8, e = kk & 255;
  wt[(size_t)k * KK_ + kk] = f2bf(conv_w[(k * E_ + e) * KS_ + j]);
}

// ---------------- prep: U_w / final_w fp32 -> fp8 (x16), K-unit-major ----------------
__global__ __launch_bounds__(256) void k_cast(const float* __restrict__ U_w,
                                              const float* __restrict__ F_w,
                                              unsigned char* __restrict__ u8,
                                              unsigned char* __restrict__ f8) {
  int gid = blockIdx.x * 256 + threadIdx.x;
  const float* src = blockIdx.y ? F_w : U_w;
  unsigned char* dst = blockIdx.y ? f8 : u8;
  int l = gid >> 6;
  int k0 = (gid & 63) << 3;
  const float* s = src + (size_t)l * K_ + k0;
  float4 v0 = *(const float4*)(s);
  float4 v1 = *(const float4*)(s + 4);
  uint2 o;
  o.x = pk4_fp8(v0.x * W_SCALE, v0.y * W_SCALE, v0.z * W_SCALE, v0.w * W_SCALE);
  o.y = pk4_fp8(v1.x * W_SCALE, v1.y * W_SCALE, v1.z * W_SCALE, v1.w * W_SCALE);
  *(uint2*)(dst + w_off(l, k0)) = o;
}

// ---------------- conv1d as MFMA GEMM (bf16 in, fp8 out x64, K-unit-major) ----------------
__global__ __launch_bounds__(512, 4) void k_conv(const unsigned short* __restrict__ xpad,
                                                 const unsigned short* __restrict__ wt,
                                                 const float* __restrict__ conv_b,
                                                 unsigned char* __restrict__ feats) {
  __shared__ char At[2][16384];
  __shared__ char Bt[2][16384];
  const int tid = threadIdx.x;
  const int lane = tid & 63;
  const int q = lane >> 4, c = lane & 15;
  const int w = tid >> 6;
  const int wi = w >> 1, wj = w & 1;
  const int b = blockIdx.z;
  const int t0 = blockIdx.y * 128;
  const int n0 = blockIdx.x * 128;

  const char* xb = (const char*)(xpad + (size_t)b * TP_ * E_);
  const char* wb = (const char*)wt;

  const char* asrc[2]; const char* bsrc[2]; int ldso[2];
#pragma unroll
  for (int rnd = 0; rnd < 2; ++rnd) {
    int u = rnd * 512 + tid;
    int r = u >> 3;
    int j = (u & 7) ^ (r & 7);
    asrc[rnd] = xb + (size_t)(t0 + r) * 512 + j * 16;
    bsrc[rnd] = wb + (size_t)(n0 + r) * (KK_ * 2) + j * 16;
    ldso[rnd] = u * 16;
  }

  int offA[2][2], offB[4][2];
#pragma unroll
  for (int li = 0; li < 2; ++li) {
    int r = wi * 32 + li * 16 + c;
#pragma unroll
    for (int h = 0; h < 2; ++h) offA[li][h] = r * 128 + (((4 * h + q) ^ (r & 7)) << 4);
  }
#pragma unroll
  for (int ti = 0; ti < 4; ++ti) {
    int r = wj * 64 + ti * 16 + c;
#pragma unroll
    for (int h = 0; h < 2; ++h) offB[ti][h] = r * 128 + (((4 * h + q) ^ (r & 7)) << 4);
  }

  f32x4 acc[2][4];
  f32x4 zero = {0.f, 0.f, 0.f, 0.f};
#pragma unroll
  for (int i = 0; i < 2; ++i)
#pragma unroll
    for (int j = 0; j < 4; ++j) acc[i][j] = zero;

#pragma unroll
  for (int rnd = 0; rnd < 2; ++rnd) {
    gld_lds16(asrc[rnd], At[0] + ldso[rnd]);
    gld_lds16(bsrc[rnd], Bt[0] + ldso[rnd]);
  }

  for (int it = 0; it < 36; ++it) {
    const int bsel = it & 1;
    __syncthreads();
    if (it != 35) {
      const int kkc = (it + 1) * 64;
      const int aofs = (kkc >> 8) * 512 + (kkc & 255) * 2;
      const int bofs = kkc * 2;
#pragma unroll
      for (int rnd = 0; rnd < 2; ++rnd) {
        gld_lds16(asrc[rnd] + aofs, At[bsel ^ 1] + ldso[rnd]);
        gld_lds16(bsrc[rnd] + bofs, Bt[bsel ^ 1] + ldso[rnd]);
      }
    }
    const char* aB = At[bsel];
    const char* bB = Bt[bsel];
#pragma unroll
    for (int h = 0; h < 2; ++h) {
      bf16x8 afr[2], bfr[4];
#pragma unroll
      for (int li = 0; li < 2; ++li) afr[li] = *(const bf16x8*)(aB + offA[li][h]);
#pragma unroll
      for (int ti = 0; ti < 4; ++ti) bfr[ti] = *(const bf16x8*)(bB + offB[ti][h]);
#pragma unroll
      for (int ti = 0; ti < 4; ++ti)
#pragma unroll
        for (int li = 0; li < 2; ++li)
          acc[li][ti] = mfma_bf16(afr[li], bfr[ti], acc[li][ti]);
    }
  }

  // epilogue: +bias, relu, fp8 store into the K-unit-major feats layout.
  const size_t fbase = (size_t)b * T_ * K_;
#pragma unroll
  for (int ti = 0; ti < 4; ++ti) {
    int k = n0 + wj * 64 + ti * 16 + c;
    float bias = conv_b[k];
#pragma unroll
    for (int li = 0; li < 2; ++li) {
      int tb = t0 + wi * 32 + li * 16 + q * 4;
#pragma unroll
      for (int rr = 0; rr < 4; ++rr) {
        float v = fmaxf(acc[li][ti][rr] + bias, 0.f) * FEAT_SCALE;
        int t = tb + rr;
        feats[fbase + f_off(t, k)] = f2fp8(v);
      }
    }
  }
}

// ---------------- fused label-attention ----------------
// R3 structure exactly (K-unit-major LDS, uf/wf in regs, __syncthreads dbuf;
// 124 us, 0 conflicts, no spill) with two local deltas:
//  (1) pair-barrier coarsening: 2 chunks (64 KB) staged per barrier -> 16
//      barrier events instead of 32 (halves drain+skew cost);
//  (2) zero-C-in MFMA: first MFMA of each chunk takes a loop-invariant zero
//      vector as C (D != C), eliminating 32 acc-reset movs per chunk.
// The dual-acc softmax-shadow axis is CLOSED: R4/R5/R6 all spilled or
// regressed (WRITE_SIZE 0.25 -> 290/46 MB at ~250+ live regs).
__global__ __launch_bounds__(512, 2) void k_attn(const unsigned char* __restrict__ feats,
                                                 const unsigned char* __restrict__ u8,
                                                 const unsigned char* __restrict__ f8,
                                                 const float* __restrict__ final_b,
                                                 float* __restrict__ out) {
  __shared__ __align__(16) char smem[131072];
  __shared__ float red[512];
  const int tid = threadIdx.x;
  const int lane = tid & 63;
  const int q2 = lane >> 5, c32 = lane & 31;
  const int w = tid >> 6;
  const int wi = w >> 1;   // L quarter (32 rows)
  const int wj = w & 1;    // T half (32 cols of the 64-col chunk)
  const int b = blockIdx.y;
  const int l0 = blockIdx.x * 128;

  const unsigned char* fb = feats + (size_t)b * T_ * K_;

  // ---- stage U/W (K-unit-major) identity into LDS: 64 KB each ----
  char* Us = smem;
  char* Ws = smem + 65536;
#pragma unroll
  for (int rr = 0; rr < 8; ++rr) {
    gld_lds16(u8 + (size_t)l0 * K_ + rr * 8192 + tid * 16, Us + rr * 8192 + tid * 16);
    gld_lds16(f8 + (size_t)l0 * K_ + rr * 8192 + tid * 16, Ws + rr * 8192 + tid * 16);
  }
  __syncthreads();

  // ---- pull full-K A-fragments into registers: 8 K-blocks x 32B each ----
  // Layout [u][128][16]: unit u at u*2048 + l_local*16. Lane needs units
  // u = s*4 + q2*2 + {0,1}  ->  base + s*8192 + {0,2048}.
  const int arow = wi * 32 + c32;
  const int abase = q2 * 4096 + arow * 16;
  i32x8 uf[8], wf[8];
#pragma unroll
  for (int s = 0; s < 8; ++s) {
    int o0 = abase + s * 8192;
    i32x4 ul = *(const i32x4*)(Us + o0);
    i32x4 uh = *(const i32x4*)(Us + o0 + 2048);
    i32x4 wl = *(const i32x4*)(Ws + o0);
    i32x4 wh = *(const i32x4*)(Ws + o0 + 2048);
    uf[s] = __builtin_shufflevector(ul, uh, 0, 1, 2, 3, 4, 5, 6, 7);
    wf[s] = __builtin_shufflevector(wl, wh, 0, 1, 2, 3, 4, 5, 6, 7);
  }
  __syncthreads();   // all waves done reading before the F buffers overwrite

  // ---- F pair double-buffer: 2 x 64 KB, each holding TWO 32 KB chunks ----
  const unsigned char* fsrc = fb + tid * 16;   // + pair*65536 + rr*8192
#pragma unroll
  for (int rr = 0; rr < 8; ++rr)
    gld_lds16(fsrc + rr * 8192, smem + tid * 16 + rr * 8192);

  // Layout [u][64][16]: unit u at u*1024 + t_local*16. Lane needs units
  // u = s*4 + q2*2 + {0,1}  ->  bbase + s*4096 + {0,1024}.
  const int brow = wj * 32 + c32;
  const int bbase = q2 * 2048 + brow * 16;

  f32x16 zc;
#pragma unroll
  for (int r = 0; r < 16; ++r) zc[r] = 0.f;   // loop-invariant zero C-in

  float num[16], den[16];
#pragma unroll
  for (int r = 0; r < 16; ++r) { num[r] = 0.f; den[r] = 0.f; }

  for (int pr = 0; pr < 16; ++pr) {
    char* const buf = smem + (pr & 1) * 65536;
    __syncthreads();   // pair pr staged; prior reads of the other buffer done
    if (pr != 15) {
      const unsigned char* nsrc = fsrc + (size_t)(pr + 1) * 65536;
      char* const nbuf = smem + ((pr + 1) & 1) * 65536;
#pragma unroll
      for (int rr = 0; rr < 8; ++rr)
        gld_lds16(nsrc + rr * 8192, nbuf + tid * 16 + rr * 8192);
    }
#pragma unroll
    for (int half = 0; half < 2; ++half) {
      const char* cur = buf + half * 32768;
      i32x4 flo = *(const i32x4*)(cur + bbase);
      i32x4 fhi = *(const i32x4*)(cur + bbase + 1024);
      i32x8 fa = __builtin_shufflevector(flo, fhi, 0, 1, 2, 3, 4, 5, 6, 7);
      f32x16 accS = mfma_sc64(uf[0], fa, zc);
      f32x16 accV = mfma_sc64(wf[0], fa, zc);
#pragma unroll
      for (int s = 1; s < 8; ++s) {
        flo = *(const i32x4*)(cur + bbase + s * 4096);
        fhi = *(const i32x4*)(cur + bbase + s * 4096 + 1024);
        fa = __builtin_shufflevector(flo, fhi, 0, 1, 2, 3, 4, 5, 6, 7);
        accS = mfma_sc64(uf[s], fa, accS);
        accV = mfma_sc64(wf[s], fa, accV);
      }
      // softmax-weighted accumulate. scores are O(0.01): exp without
      // max-shift is safe. num carries the raw 1024x V scale; INV_SS is
      // folded once at the final write.
#pragma unroll
      for (int r = 0; r < 16; ++r) {
        float p = __builtin_exp2f(accS[r] * INV_SS_LOG2E);
        den[r] += p;
        num[r] += p * accV[r];
      }
    }
  }

  // reduce over 32 t-columns (c32 lanes; q2 halves hold different L-rows)
#pragma unroll
  for (int r = 0; r < 16; ++r) {
#pragma unroll
    for (int m = 1; m < 32; m <<= 1) {
      num[r] += __shfl_xor(num[r], m, 64);
      den[r] += __shfl_xor(den[r], m, 64);
    }
  }
  if (c32 == 0) {
#pragma unroll
    for (int r = 0; r < 16; ++r) {
      // C/D 32x32: row = (reg&3) + 8*(reg>>2) + 4*(lane>>5)
      int ll = wi * 32 + (r & 3) + 8 * (r >> 2) + 4 * q2;
      red[wj * 256 + ll] = num[r];
      red[wj * 256 + 128 + ll] = den[r];
    }
  }
  __syncthreads();
  if (tid < 128) {
    int l = l0 + tid;
    float n = red[tid] + red[256 + tid];
    float d = red[128 + tid] + red[384 + tid];
    out[(size_t)b * L_ + l] = (n * INV_SS) / d + final_b[l];
  }
}

// ---------------- BCE-with-logits mean ----------------
__global__ __launch_bounds__(256) void k_loss(const float* __restrict__ yhat,
                                              const float* __restrict__ target,
                                              float* __restrict__ loss) {
  int gid = blockIdx.x * 256 + threadIdx.x;
  float s = 0.f;
  for (int i = gid; i < B_ * L_; i += 64 * 256) {
    float y = yhat[i], t = target[i];
    s += fmaxf(y, 0.f) - y * t + log1pf(__expf(-fabsf(y)));
  }
#pragma unroll
  for (int m = 1; m < 64; m <<= 1) s += __shfl_xor(s, m, 64);
  if ((threadIdx.x & 63) == 0) atomicAdd(loss, s * (1.0f / (B_ * L_)));
}

extern "C" void kernel_launch(void* const* d_in, const int* in_sizes, int n_in,
                              void* d_out, int out_size, void* d_ws, size_t ws_size,
                              hipStream_t stream) {
  const int* ids = (const int*)d_in[0];
  const float* target = (const float*)d_in[3];
  const float* emb = (const float*)d_in[4];
  const float* conv_w = (const float*)d_in[5];
  const float* conv_b = (const float*)d_in[6];
  const float* U_w = (const float*)d_in[7];
  const float* F_w = (const float*)d_in[8];
  const float* final_b = (const float*)d_in[9];
  float* out = (float*)d_out;

  char* ws = (char*)d_ws;
  unsigned short* xpad = (unsigned short*)ws;                    // bf16 B*TP*E
  size_t off = (size_t)B_ * TP_ * E_ * 2;
  unsigned short* wt = (unsigned short*)(ws + off);              // bf16 K*KK
  off += (size_t)K_ * KK_ * 2;
  unsigned char* u8 = (unsigned char*)(ws + off);                // fp8 L*K (unit-major)
  off += (size_t)L_ * K_;
  unsigned char* f8 = (unsigned char*)(ws + off);                // fp8 L*K (unit-major)
  off += (size_t)L_ * K_;
  unsigned char* feats = (unsigned char*)(ws + off);             // fp8 B*T*K (unit-major)
  off += (size_t)B_ * T_ * K_;
  if (ws_size < off) return;

  k_embed<<<dim3((B_ * TP_ * 64) / 256), 256, 0, stream>>>(ids, emb, xpad);
  k_wt<<<dim3(KK_ / 256, K_), 256, 0, stream>>>(conv_w, wt);
  k_cast<<<dim3((L_ * K_ / 8) / 256, 2), 256, 0, stream>>>(U_w, F_w, u8, f8);
  k_conv<<<dim3(K_ / 128, T_ / 128, B_), 512, 0, stream>>>(xpad, wt, conv_b, feats);
  k_attn<<<dim3(L_ / 128, B_), 512, 0, stream>>>(feats, u8, f8, final_b, out);
  hipMemsetAsync(out + B_ * L_, 0, sizeof(float), stream);
  k_loss<<<dim3(64), 256, 0, stream>>>(out, target, out + B_ * L_);
}

// Round 8
// 289.414 us; speedup vs baseline: 1.7752x; 1.0467x over previous
//
#include <hip/hip_runtime.h>
#include <hip/hip_bf16.h>
#include <cstdint>

#define B_ 8
#define T_ 2048
#define E_ 256
#define K_ 512
#define KS_ 9
#define L_ 8192
#define PAD_ 4
#define TP_ (T_ + 2 * PAD_)   // 2056
#define KK_ (E_ * KS_)        // 2304

// fp8 scaling: feats stored as fp8*64, U/final stored as fp8*16.
// S and V accumulators are 1024x true value -> multiply by 2^-10 in epilogue.
#define FEAT_SCALE 64.0f
#define W_SCALE 16.0f
#define INV_SS 9.765625e-4f         // 2^-10
#define INV_SS_LOG2E 1.40888719e-3f // 2^-10 * log2(e)

// merged-prep block ranges
#define NB_EMBED ((B_ * TP_ * 64) / 256)          // 4112
#define NB_WT ((K_ * KK_) / 256)                  // 4608
#define NB_CAST ((2 * L_ * K_ / 8) / 256)         // 4096

typedef __bf16 bf16x8 __attribute__((ext_vector_type(8)));
typedef float f32x4 __attribute__((ext_vector_type(4)));
typedef float f32x16 __attribute__((ext_vector_type(16)));
typedef int i32x4 __attribute__((ext_vector_type(4)));
typedef int i32x8 __attribute__((ext_vector_type(8)));

__device__ __forceinline__ unsigned short f2bf(float f) {
  union { float f; unsigned int u; } a; a.f = f;
  unsigned int r = (a.u + 0x7FFFu + ((a.u >> 16) & 1u)) >> 16;
  return (unsigned short)r;
}

__device__ __forceinline__ unsigned char f2fp8(float v) {
  return (unsigned char)(__builtin_amdgcn_cvt_pk_fp8_f32(v, v, 0, false) & 0xFF);
}

__device__ __forceinline__ unsigned int pk4_fp8(float a, float b, float c, float d) {
  int v = __builtin_amdgcn_cvt_pk_fp8_f32(a, b, 0, false);
  v = __builtin_amdgcn_cvt_pk_fp8_f32(c, d, v, true);
  return (unsigned int)v;
}

__device__ __forceinline__ void gld_lds16(const void* g, void* l) {
  __builtin_amdgcn_global_load_lds(
      (const __attribute__((address_space(1))) unsigned int*)g,
      (__attribute__((address_space(3))) unsigned int*)l, 16, 0, 0);
}

__device__ __forceinline__ f32x4 mfma_bf16(bf16x8 a, bf16x8 b, f32x4 c) {
  return __builtin_amdgcn_mfma_f32_16x16x32_bf16(a, b, c, 0, 0, 0);
}

// MX-scaled fp8 MFMA, K=64, unity e8m0 scales (0x7F -> 2^0). 2x non-scaled rate.
__device__ __forceinline__ f32x16 mfma_sc64(i32x8 a, i32x8 b, f32x16 c) {
  return __builtin_amdgcn_mfma_scale_f32_32x32x64_f8f6f4(a, b, c, 0, 0, 0, 127, 0, 127);
}

// K-unit-major (16B) layouts — the HW-verified conflict-free pattern (R3:
// SQ_LDS_BANK_CONFLICT 8.9M -> 0). Fragment reads: 32 lanes x 16B contiguous
// (512 B per half-wave). 32B-stride variants reintroduce conflicts (R5).
// feats per batch: [tc = t>>6][u = k>>4][t&63][k&15]  (32 KB per t-chunk)
__device__ __forceinline__ int f_off(int t, int k) {
  return ((t >> 6) * 32768) + (((k >> 4) * 64 + (t & 63)) << 4) + (k & 15);
}
// U/W: [lb = l>>7][u = k>>4][l&127][k&15]  (64 KB per l-block)
__device__ __forceinline__ int w_off(int l, int k) {
  return ((l >> 7) * 65536) + (((k >> 4) * 128 + (l & 127)) << 4) + (k & 15);
}

// ---------------- merged prep: embed-gather | conv_w transpose | U/F cast ----
// The three prep stages are mutually independent; one launch lets them
// overlap on the CUs instead of serializing as 3 stream-ordered kernels.
__global__ __launch_bounds__(256) void k_prep(const int* __restrict__ ids,
                                              const float* __restrict__ emb,
                                              const float* __restrict__ conv_w,
                                              const float* __restrict__ U_w,
                                              const float* __restrict__ F_w,
                                              unsigned short* __restrict__ xpad,
                                              unsigned short* __restrict__ wt,
                                              unsigned char* __restrict__ u8,
                                              unsigned char* __restrict__ f8) {
  const int bx = blockIdx.x;
  const int tid = threadIdx.x;
  if (bx < NB_EMBED) {
    // ---- embed gather + zero halo, cast to bf16 ----
    int gid = bx * 256 + tid;
    int row = gid >> 6;
    int e4 = (gid & 63) << 2;
    int b = row / TP_;
    int tp = row - b * TP_;
    float4 v = make_float4(0.f, 0.f, 0.f, 0.f);
    if (tp >= PAD_ && tp < T_ + PAD_) {
      int id = ids[b * T_ + tp - PAD_];
      v = *(const float4*)(emb + (size_t)id * E_ + e4);
    }
    ushort4 o;
    o.x = f2bf(v.x); o.y = f2bf(v.y); o.z = f2bf(v.z); o.w = f2bf(v.w);
    *(ushort4*)(xpad + (size_t)row * E_ + e4) = o;
  } else if (bx < NB_EMBED + NB_WT) {
    // ---- conv_w [K,E,KS] -> W_t [K][j*256+e] bf16 ----
    int g = (bx - NB_EMBED) * 256 + tid;
    int k = g / KK_;
    int kk = g - k * KK_;
    int j = kk >> 8, e = kk & 255;
    wt[(size_t)k * KK_ + kk] = f2bf(conv_w[(k * E_ + e) * KS_ + j]);
  } else {
    // ---- U_w / final_w fp32 -> fp8 (x16), K-unit-major ----
    int g = (bx - NB_EMBED - NB_WT) * 256 + tid;   // 0 .. 2^20-1
    int sel = g >> 19;                              // 0 = U, 1 = F
    int gid = g & ((1 << 19) - 1);
    const float* src = sel ? F_w : U_w;
    unsigned char* dst = sel ? f8 : u8;
    int l = gid >> 6;
    int k0 = (gid & 63) << 3;
    const float* s = src + (size_t)l * K_ + k0;
    float4 v0 = *(const float4*)(s);
    float4 v1 = *(const float4*)(s + 4);
    uint2 o;
    o.x = pk4_fp8(v0.x * W_SCALE, v0.y * W_SCALE, v0.z * W_SCALE, v0.w * W_SCALE);
    o.y = pk4_fp8(v1.x * W_SCALE, v1.y * W_SCALE, v1.z * W_SCALE, v1.w * W_SCALE);
    *(uint2*)(dst + w_off(l, k0)) = o;
  }
}

// ---------------- conv1d as MFMA GEMM (bf16 in, fp8 out x64, K-unit-major) ----------------
__global__ __launch_bounds__(512, 4) void k_conv(const unsigned short* __restrict__ xpad,
                                                 const unsigned short* __restrict__ wt,
                                                 const float* __restrict__ conv_b,
                                                 unsigned char* __restrict__ feats) {
  __shared__ char At[2][16384];
  __shared__ char Bt[2][16384];
  const int tid = threadIdx.x;
  const int lane = tid & 63;
  const int q = lane >> 4, c = lane & 15;
  const int w = tid >> 6;
  const int wi = w >> 1, wj = w & 1;
  const int b = blockIdx.z;
  const int t0 = blockIdx.y * 128;
  const int n0 = blockIdx.x * 128;

  const char* xb = (const char*)(xpad + (size_t)b * TP_ * E_);
  const char* wb = (const char*)wt;

  const char* asrc[2]; const char* bsrc[2]; int ldso[2];
#pragma unroll
  for (int rnd = 0; rnd < 2; ++rnd) {
    int u = rnd * 512 + tid;
    int r = u >> 3;
    int j = (u & 7) ^ (r & 7);
    asrc[rnd] = xb + (size_t)(t0 + r) * 512 + j * 16;
    bsrc[rnd] = wb + (size_t)(n0 + r) * (KK_ * 2) + j * 16;
    ldso[rnd] = u * 16;
  }

  int offA[2][2], offB[4][2];
#pragma unroll
  for (int li = 0; li < 2; ++li) {
    int r = wi * 32 + li * 16 + c;
#pragma unroll
    for (int h = 0; h < 2; ++h) offA[li][h] = r * 128 + (((4 * h + q) ^ (r & 7)) << 4);
  }
#pragma unroll
  for (int ti = 0; ti < 4; ++ti) {
    int r = wj * 64 + ti * 16 + c;
#pragma unroll
    for (int h = 0; h < 2; ++h) offB[ti][h] = r * 128 + (((4 * h + q) ^ (r & 7)) << 4);
  }

  f32x4 acc[2][4];
  f32x4 zero = {0.f, 0.f, 0.f, 0.f};
#pragma unroll
  for (int i = 0; i < 2; ++i)
#pragma unroll
    for (int j = 0; j < 4; ++j) acc[i][j] = zero;

#pragma unroll
  for (int rnd = 0; rnd < 2; ++rnd) {
    gld_lds16(asrc[rnd], At[0] + ldso[rnd]);
    gld_lds16(bsrc[rnd], Bt[0] + ldso[rnd]);
  }

  for (int it = 0; it < 36; ++it) {
    const int bsel = it & 1;
    __syncthreads();
    if (it != 35) {
      const int kkc = (it + 1) * 64;
      const int aofs = (kkc >> 8) * 512 + (kkc & 255) * 2;
      const int bofs = kkc * 2;
#pragma unroll
      for (int rnd = 0; rnd < 2; ++rnd) {
        gld_lds16(asrc[rnd] + aofs, At[bsel ^ 1] + ldso[rnd]);
        gld_lds16(bsrc[rnd] + bofs, Bt[bsel ^ 1] + ldso[rnd]);
      }
    }
    const char* aB = At[bsel];
    const char* bB = Bt[bsel];
#pragma unroll
    for (int h = 0; h < 2; ++h) {
      bf16x8 afr[2], bfr[4];
#pragma unroll
      for (int li = 0; li < 2; ++li) afr[li] = *(const bf16x8*)(aB + offA[li][h]);
#pragma unroll
      for (int ti = 0; ti < 4; ++ti) bfr[ti] = *(const bf16x8*)(bB + offB[ti][h]);
#pragma unroll
      for (int ti = 0; ti < 4; ++ti)
#pragma unroll
        for (int li = 0; li < 2; ++li)
          acc[li][ti] = mfma_bf16(afr[li], bfr[ti], acc[li][ti]);
    }
  }

  // epilogue: +bias, relu, fp8 store into the K-unit-major feats layout.
  const size_t fbase = (size_t)b * T_ * K_;
#pragma unroll
  for (int ti = 0; ti < 4; ++ti) {
    int k = n0 + wj * 64 + ti * 16 + c;
    float bias = conv_b[k];
#pragma unroll
    for (int li = 0; li < 2; ++li) {
      int tb = t0 + wi * 32 + li * 16 + q * 4;
#pragma unroll
      for (int rr = 0; rr < 4; ++rr) {
        float v = fmaxf(acc[li][ti][rr] + bias, 0.f) * FEAT_SCALE;
        int t = tb + rr;
        feats[fbase + f_off(t, k)] = f2fp8(v);
      }
    }
  }
}

// ---------------- fused label-attention ----------------
// EXACT R3 structure (best measured: 124.2 us, MfmaUtil 48%, 0 conflicts,
// no spill): K-unit-major LDS, uf/wf in regs, 32-chunk __syncthreads dbuf.
// Only delta vs R3: zero-C first MFMA per chunk (D != C is legal), removing
// the 32 acc-reset movs per chunk. CLOSED axes (measured): dual-acc softmax
// shadow (R4/5/6: spill/regress), counted-vmcnt ring (R4: +33us stall),
// pair-barrier coarsening (R7: +15us stall). At the barrier only the 4
// prefetch loads issued a full chunk earlier are outstanding -> drain is
// already free; residual stall is lockstep skew at 2 waves/SIMD, which is
// pinned by the 128-reg uf/wf footprint (4 waves/SIMD needs <=128 total).
__global__ __launch_bounds__(512, 2) void k_attn(const unsigned char* __restrict__ feats,
                                                 const unsigned char* __restrict__ u8,
                                                 const unsigned char* __restrict__ f8,
                                                 const float* __restrict__ final_b,
                                                 float* __restrict__ out) {
  __shared__ __align__(16) char smem[131072];
  __shared__ float red[512];
  const int tid = threadIdx.x;
  const int lane = tid & 63;
  const int q2 = lane >> 5, c32 = lane & 31;
  const int w = tid >> 6;
  const int wi = w >> 1;   // L quarter (32 rows)
  const int wj = w & 1;    // T half (32 cols of the 64-col chunk)
  const int b = blockIdx.y;
  const int l0 = blockIdx.x * 128;

  const unsigned char* fb = feats + (size_t)b * T_ * K_;

  // ---- stage U/W (K-unit-major) identity into LDS: 64 KB each ----
  char* Us = smem;
  char* Ws = smem + 65536;
#pragma unroll
  for (int rr = 0; rr < 8; ++rr) {
    gld_lds16(u8 + (size_t)l0 * K_ + rr * 8192 + tid * 16, Us + rr * 8192 + tid * 16);
    gld_lds16(f8 + (size_t)l0 * K_ + rr * 8192 + tid * 16, Ws + rr * 8192 + tid * 16);
  }
  __syncthreads();

  // ---- pull full-K A-fragments into registers: 8 K-blocks x 32B each ----
  // Layout [u][128][16]: unit u at u*2048 + l_local*16. Lane needs units
  // u = s*4 + q2*2 + {0,1}  ->  base + s*8192 + {0,2048}.
  const int arow = wi * 32 + c32;
  const int abase = q2 * 4096 + arow * 16;
  i32x8 uf[8], wf[8];
#pragma unroll
  for (int s = 0; s < 8; ++s) {
    int o0 = abase + s * 8192;
    i32x4 ul = *(const i32x4*)(Us + o0);
    i32x4 uh = *(const i32x4*)(Us + o0 + 2048);
    i32x4 wl = *(const i32x4*)(Ws + o0);
    i32x4 wh = *(const i32x4*)(Ws + o0 + 2048);
    uf[s] = __builtin_shufflevector(ul, uh, 0, 1, 2, 3, 4, 5, 6, 7);
    wf[s] = __builtin_shufflevector(wl, wh, 0, 1, 2, 3, 4, 5, 6, 7);
  }
  __syncthreads();   // all waves done reading before F overwrites this region

  // ---- F double-buffer in the same LDS: 2 x 32 KB ([u][64][16] per chunk) ----
  char* const Fs0 = smem;
  char* const Fs1 = smem + 32768;
  const unsigned char* fsrc = fb + tid * 16;   // + tc*32768 + rr*8192
#pragma unroll
  for (int rr = 0; rr < 4; ++rr)
    gld_lds16(fsrc + rr * 8192, Fs0 + tid * 16 + rr * 8192);

  // Layout [u][64][16]: unit u at u*1024 + t_local*16. Lane needs units
  // u = s*4 + q2*2 + {0,1}  ->  bbase + s*4096 + {0,1024}.
  const int brow = wj * 32 + c32;
  const int bbase = q2 * 2048 + brow * 16;

  f32x16 zc;
#pragma unroll
  for (int r = 0; r < 16; ++r) zc[r] = 0.f;   // loop-invariant zero C-in

  float num[16], den[16];
#pragma unroll
  for (int r = 0; r < 16; ++r) { num[r] = 0.f; den[r] = 0.f; }

  for (int tc = 0; tc < 32; ++tc) {
    const int bsel = tc & 1;
    char* const cur = bsel ? Fs1 : Fs0;
    char* const nxt = bsel ? Fs0 : Fs1;
    __syncthreads();   // chunk tc staged; prior reads of the other buffer done
    if (tc != 31) {
      const unsigned char* nsrc = fsrc + (size_t)(tc + 1) * 32768;
#pragma unroll
      for (int rr = 0; rr < 4; ++rr)
        gld_lds16(nsrc + rr * 8192, nxt + tid * 16 + rr * 8192);
    }
    f32x16 accS, accV;
    {
      i32x4 flo = *(const i32x4*)(cur + bbase);
      i32x4 fhi = *(const i32x4*)(cur + bbase + 1024);
      i32x8 fa = __builtin_shufflevector(flo, fhi, 0, 1, 2, 3, 4, 5, 6, 7);
      accS = mfma_sc64(uf[0], fa, zc);
      accV = mfma_sc64(wf[0], fa, zc);
    }
#pragma unroll
    for (int s = 1; s < 8; ++s) {
      i32x4 flo = *(const i32x4*)(cur + bbase + s * 4096);
      i32x4 fhi = *(const i32x4*)(cur + bbase + s * 4096 + 1024);
      i32x8 fa = __builtin_shufflevector(flo, fhi, 0, 1, 2, 3, 4, 5, 6, 7);
      accS = mfma_sc64(uf[s], fa, accS);
      accV = mfma_sc64(wf[s], fa, accV);
    }
    // softmax-weighted accumulate. scores are O(0.01): exp without max-shift
    // is safe. num carries the raw 1024x V scale; INV_SS folded at the write.
#pragma unroll
    for (int r = 0; r < 16; ++r) {
      float p = __builtin_exp2f(accS[r] * INV_SS_LOG2E);
      den[r] += p;
      num[r] += p * accV[r];
    }
  }

  // reduce over 32 t-columns (c32 lanes; q2 halves hold different L-rows)
#pragma unroll
  for (int r = 0; r < 16; ++r) {
#pragma unroll
    for (int m = 1; m < 32; m <<= 1) {
      num[r] += __shfl_xor(num[r], m, 64);
      den[r] += __shfl_xor(den[r], m, 64);
    }
  }
  if (c32 == 0) {
#pragma unroll
    for (int r = 0; r < 16; ++r) {
      // C/D 32x32: row = (reg&3) + 8*(reg>>2) + 4*(lane>>5)
      int ll = wi * 32 + (r & 3) + 8 * (r >> 2) + 4 * q2;
      red[wj * 256 + ll] = num[r];
      red[wj * 256 + 128 + ll] = den[r];
    }
  }
  __syncthreads();
  if (tid < 128) {
    int l = l0 + tid;
    float n = red[tid] + red[256 + tid];
    float d = red[128 + tid] + red[384 + tid];
    out[(size_t)b * L_ + l] = (n * INV_SS) / d + final_b[l];
  }
}

// ---------------- BCE-with-logits mean ----------------
__global__ __launch_bounds__(256) void k_loss(const float* __restrict__ yhat,
                                              const float* __restrict__ target,
                                              float* __restrict__ loss) {
  int gid = blockIdx.x * 256 + threadIdx.x;
  float s = 0.f;
  for (int i = gid; i < B_ * L_; i += 64 * 256) {
    float y = yhat[i], t = target[i];
    s += fmaxf(y, 0.f) - y * t + log1pf(__expf(-fabsf(y)));
  }
#pragma unroll
  for (int m = 1; m < 64; m <<= 1) s += __shfl_xor(s, m, 64);
  if ((threadIdx.x & 63) == 0) atomicAdd(loss, s * (1.0f / (B_ * L_)));
}

extern "C" void kernel_launch(void* const* d_in, const int* in_sizes, int n_in,
                              void* d_out, int out_size, void* d_ws, size_t ws_size,
                              hipStream_t stream) {
  const int* ids = (const int*)d_in[0];
  const float* target = (const float*)d_in[3];
  const float* emb = (const float*)d_in[4];
  const float* conv_w = (const float*)d_in[5];
  const float* conv_b = (const float*)d_in[6];
  const float* U_w = (const float*)d_in[7];
  const float* F_w = (const float*)d_in[8];
  const float* final_b = (const float*)d_in[9];
  float* out = (float*)d_out;

  char* ws = (char*)d_ws;
  unsigned short* xpad = (unsigned short*)ws;                    // bf16 B*TP*E
  size_t off = (size_t)B_ * TP_ * E_ * 2;
  unsigned short* wt = (unsigned short*)(ws + off);              // bf16 K*KK
  off += (size_t)K_ * KK_ * 2;
  unsigned char* u8 = (unsigned char*)(ws + off);                // fp8 L*K (unit-major)
  off += (size_t)L_ * K_;
  unsigned char* f8 = (unsigned char*)(ws + off);                // fp8 L*K (unit-major)
  off += (size_t)L_ * K_;
  unsigned char* feats = (unsigned char*)(ws + off);             // fp8 B*T*K (unit-major)
  off += (size_t)B_ * T_ * K_;
  if (ws_size < off) return;

  k_prep<<<dim3(NB_EMBED + NB_WT + NB_CAST), 256, 0, stream>>>(
      ids, emb, conv_w, U_w, F_w, xpad, wt, u8, f8);
  hipMemsetAsync(out + B_ * L_, 0, sizeof(float), stream);
  k_conv<<<dim3(K_ / 128, T_ / 128, B_), 512, 0, stream>>>(xpad, wt, conv_b, feats);
  k_attn<<<dim3(L_ / 128, B_), 512, 0, stream>>>(feats, u8, f8, final_b, out);
  k_loss<<<dim3(64), 256, 0, stream>>>(out, target, out + B_ * L_);
}